// Round 10
// baseline (534.858 us; speedup 1.0000x reference)
//
#include <hip/hip_runtime.h>

#define N_USERS 100000
#define N_ITEMS 50000
#define N_NODES 150000
#define HH 64
#define NEDGES 1200000
#define NQ 16384
#define LN_EPS 1e-5f
#define SCAN_NBLK 147   // ceil(150000/1024)

// ---------------------------------------------------------------------------
// GEMM micro-tile: 64 rows x 64 cols per block, 256 threads, 4x4 per thread.
// As[r][68] row-major, k-chunk position XOR-swizzled by (r>>3)&3 (verified
// 0 conflicts on HW, round 7). LDS 34.8KB -> 4 blocks/CU (16 waves).
// Staging split into load(regs)/write(LDS): next-phase global loads issued
// BEFORE the current gemm so they complete under it.
// ---------------------------------------------------------------------------
#define SA 68
#define SW 68

__device__ __forceinline__ void loadA4(float4 aR[4], const float* __restrict__ src,
                                       int row0, int M, int stride, int koff, int t)
{
#pragma unroll
    for (int i = 0; i < 4; ++i) {
        int f4 = t + i * 256;              // 64 rows x 16 float4
        int r = f4 >> 4, k4 = f4 & 15;
        int gr = row0 + r;
        aR[i] = make_float4(0.f, 0.f, 0.f, 0.f);
        if (gr < M) aR[i] = *(const float4*)&src[(size_t)gr * stride + koff + k4 * 4];
    }
}

__device__ __forceinline__ void writeA4(float* __restrict__ As, const float4 aR[4], int t)
{
#pragma unroll
    for (int i = 0; i < 4; ++i) {
        int f4 = t + i * 256;
        int r = f4 >> 4, k4 = f4 & 15;
        *(float4*)&As[r * SA + ((k4 ^ ((r >> 3) & 3)) << 2)] = aR[i];
    }
}

__device__ __forceinline__ void loadW4(float4 wR[4], const float* __restrict__ W,
                                       int KW, int koff, int t)
{
#pragma unroll
    for (int i = 0; i < 4; ++i) {
        int idx = t + i * 256;
        int n = idx & 63, k4 = idx >> 6;
        wR[i] = *(const float4*)&W[(size_t)n * KW + koff + k4 * 4];
    }
}

__device__ __forceinline__ void writeW4(float* __restrict__ Ws, const float4 wR[4], int t)
{
#pragma unroll
    for (int i = 0; i < 4; ++i) {
        int idx = t + i * 256;
        int n = idx & 63, k4 = idx >> 6;
        Ws[(k4 * 4 + 0) * SW + n] = wR[i].x;
        Ws[(k4 * 4 + 1) * SW + n] = wR[i].y;
        Ws[(k4 * 4 + 2) * SW + n] = wR[i].z;
        Ws[(k4 * 4 + 3) * SW + n] = wR[i].w;
    }
}

__device__ __forceinline__ void gemm_4x4(const float* __restrict__ As,
                                         const float* __restrict__ Ws,
                                         int r0, int n0, int rgm, float acc[4][4])
{
#pragma unroll 4
    for (int k4c = 0; k4c < 16; ++k4c) {
        int aoff = ((k4c ^ rgm) << 2);
        float4 a[4], w[4];
#pragma unroll
        for (int j = 0; j < 4; ++j)
            a[j] = *(const float4*)&As[(r0 + j) * SA + aoff];
#pragma unroll
        for (int kk = 0; kk < 4; ++kk)
            w[kk] = *(const float4*)&Ws[(k4c * 4 + kk) * SW + n0];
#pragma unroll
        for (int j = 0; j < 4; ++j) {
            float av[4] = { a[j].x, a[j].y, a[j].z, a[j].w };
#pragma unroll
            for (int kk = 0; kk < 4; ++kk) {
                acc[j][0] += av[kk] * (&w[kk].x)[0];
                acc[j][1] += av[kk] * (&w[kk].x)[1];
                acc[j][2] += av[kk] * (&w[kk].x)[2];
                acc[j][3] += av[kk] * (&w[kk].x)[3];
            }
        }
    }
}

// bias+ReLU+LayerNorm for 4 rows x 4 cols; row's 64 cols live in 16 lanes.
__device__ __forceinline__ void relu_ln44(const float acc[4][4], float y[4][4],
                                          const float* __restrict__ bias,
                                          const float* __restrict__ g,
                                          const float* __restrict__ be, int n0)
{
    float bv[4] = { bias[n0], bias[n0 + 1], bias[n0 + 2], bias[n0 + 3] };
    float gv[4] = { g[n0], g[n0 + 1], g[n0 + 2], g[n0 + 3] };
    float bev[4] = { be[n0], be[n0 + 1], be[n0 + 2], be[n0 + 3] };
#pragma unroll
    for (int j = 0; j < 4; ++j) {
        float yj[4];
#pragma unroll
        for (int i = 0; i < 4; ++i)
            yj[i] = fmaxf(acc[j][i] + bv[i], 0.f);
        float s = yj[0] + yj[1] + yj[2] + yj[3];
        s += __shfl_xor(s, 1); s += __shfl_xor(s, 2);
        s += __shfl_xor(s, 4); s += __shfl_xor(s, 8);
        float mean = s * (1.f / 64.f);
        float d0 = yj[0] - mean, d1 = yj[1] - mean;
        float d2 = yj[2] - mean, d3 = yj[3] - mean;
        float q = d0 * d0 + d1 * d1 + d2 * d2 + d3 * d3;
        q += __shfl_xor(q, 1); q += __shfl_xor(q, 2);
        q += __shfl_xor(q, 4); q += __shfl_xor(q, 8);
        float inv = rsqrtf(q * (1.f / 64.f) + LN_EPS);
#pragma unroll
        for (int i = 0; i < 4; ++i)
            y[j][i] = (yj[i] - mean) * inv * gv[i] + bev[i];
    }
}

// ---------------------------------------------------------------------------
// Mega-kernel: blocks [0, encB) run the fused encoder (+ GCN-L1 linear);
// blocks [encB, ...) run the edge histogram.
// Encoder: enc = LN(relu(feat@W1.T+b1)); x0 = LN(relu([enc|emb]@W2.T+b2));
//          z = x0;  B1 = x0 @ gW0.T + gb0.
// ---------------------------------------------------------------------------
__global__ __launch_bounds__(256)
void encode_hist_kernel(int ublocks, int encB,
                        const float* __restrict__ ufeat, const float* __restrict__ ifeat,
                        const float* __restrict__ uW1, const float* __restrict__ iW1,
                        const float* __restrict__ ub1, const float* __restrict__ ib1,
                        const float* __restrict__ ug1, const float* __restrict__ ig1,
                        const float* __restrict__ ube1, const float* __restrict__ ibe1,
                        const float* __restrict__ uemb, const float* __restrict__ iemb,
                        const float* __restrict__ uW2, const float* __restrict__ iW2,
                        const float* __restrict__ ub2, const float* __restrict__ ib2,
                        const float* __restrict__ ug2, const float* __restrict__ ig2,
                        const float* __restrict__ ube2, const float* __restrict__ ibe2,
                        const float* __restrict__ gW0, const float* __restrict__ gb0,
                        float* __restrict__ z, float* __restrict__ B1,
                        const int* __restrict__ adj_rows, int* __restrict__ counts)
{
    const int bid = blockIdx.x;
    const int t = threadIdx.x;

    // ---- histogram role ----
    if (bid >= encB) {
        int e = (bid - encB) * 256 + t;
        if (e < NEDGES) atomicAdd(&counts[adj_rows[e]], 1);
        return;
    }

    __shared__ float As[64 * SA];   // 17.4 KB
    __shared__ float Ws[64 * SW];   // 17.4 KB

    const bool isU = bid < ublocks;
    const float* feat = isU ? ufeat : ifeat;
    const float* W1 = isU ? uW1 : iW1;
    const float* b1 = isU ? ub1 : ib1;
    const float* g1 = isU ? ug1 : ig1;
    const float* be1 = isU ? ube1 : ibe1;
    const float* emb = isU ? uemb : iemb;
    const float* W2 = isU ? uW2 : iW2;
    const float* b2 = isU ? ub2 : ib2;
    const float* g2 = isU ? ug2 : ig2;
    const float* be2 = isU ? ube2 : ibe2;
    const int M = isU ? N_USERS : N_ITEMS;
    const int yoff = isU ? 0 : N_USERS;
    const int row0 = (isU ? bid : bid - ublocks) * 64;

    const int cg = t & 15;
    const int r0 = 4 * (t >> 4), n0 = cg * 4;
    const int rgm = (t >> 5) & 3;   // == ((r0>>3)&3), constant over r0..r0+3

    float4 aR[4], wR[4];

    // ---- P0 stage: feat c0, W1 c0 ----
    loadA4(aR, feat, row0, M, 128, 0, t);
    loadW4(wR, W1, 128, 0, t);
    writeA4(As, aR, t);
    writeW4(Ws, wR, t);
    __syncthreads();

    // ---- P0 body: issue P1 loads, gemm P0 ----
    float acc[4][4] = {};
    loadA4(aR, feat, row0, M, 128, 64, t);
    loadW4(wR, W1, 128, 64, t);
    gemm_4x4(As, Ws, r0, n0, rgm, acc);
    __syncthreads();
    writeA4(As, aR, t);
    writeW4(Ws, wR, t);
    __syncthreads();

    // ---- P1 body: issue P2 loads (W2 c0), gemm P1, relu+LN ----
    loadW4(wR, W2, 128, 0, t);
    gemm_4x4(As, Ws, r0, n0, rgm, acc);
    float y[4][4];
    relu_ln44(acc, y, b1, g1, be1, n0);
    __syncthreads();
    // P2 stage: enc y -> As (swizzled), W2 c0 -> Ws
#pragma unroll
    for (int i = 0; i < 4; ++i)
#pragma unroll
        for (int j = 0; j < 4; ++j)
            As[(r0 + j) * SA + ((cg ^ rgm) << 2) + i] = y[j][i];
    writeW4(Ws, wR, t);
    __syncthreads();

    // ---- P2 body: issue P3 loads (emb, W2 c1), gemm P2 ----
    float acc2[4][4] = {};
    loadA4(aR, emb, row0, M, 64, 0, t);
    loadW4(wR, W2, 128, 64, t);
    gemm_4x4(As, Ws, r0, n0, rgm, acc2);
    __syncthreads();
    writeA4(As, aR, t);
    writeW4(Ws, wR, t);
    __syncthreads();

    // ---- P3 body: issue P4 loads (gcn W0), gemm P3, relu+LN -> x0 ----
    loadW4(wR, gW0, 64, 0, t);
    gemm_4x4(As, Ws, r0, n0, rgm, acc2);
    float y2[4][4];
    relu_ln44(acc2, y2, b2, g2, be2, n0);
    // write z = x0
#pragma unroll
    for (int j = 0; j < 4; ++j) {
        int gr = row0 + r0 + j;
        if (gr < M)
            *(float4*)&z[(size_t)(yoff + gr) * HH + n0] =
                make_float4(y2[j][0], y2[j][1], y2[j][2], y2[j][3]);
    }
    __syncthreads();
    // P4 stage: x0 -> As, gW0 -> Ws
#pragma unroll
    for (int i = 0; i < 4; ++i)
#pragma unroll
        for (int j = 0; j < 4; ++j)
            As[(r0 + j) * SA + ((cg ^ rgm) << 2) + i] = y2[j][i];
    writeW4(Ws, wR, t);
    __syncthreads();

    // ---- P4 body: gemm L1, add gcn bias, write B1 ----
    float acc3[4][4] = {};
    gemm_4x4(As, Ws, r0, n0, rgm, acc3);
    float gbv[4] = { gb0[n0], gb0[n0 + 1], gb0[n0 + 2], gb0[n0 + 3] };
#pragma unroll
    for (int j = 0; j < 4; ++j) {
        int gr = row0 + r0 + j;
        if (gr < M)
            *(float4*)&B1[(size_t)(yoff + gr) * HH + n0] =
                make_float4(acc3[j][0] + gbv[0], acc3[j][1] + gbv[1],
                            acc3[j][2] + gbv[2], acc3[j][3] + gbv[3]);
    }
}

// ---------------------------------------------------------------------------
// GCN linear (layer 2 only): Y = X@W.T + b, K=64, 64-row blocks.
// ---------------------------------------------------------------------------
__global__ __launch_bounds__(256)
void linear64_kernel(const float* __restrict__ X, const float* __restrict__ W,
                     const float* __restrict__ bias, float* __restrict__ Y, int M)
{
    __shared__ float As[64 * SA];
    __shared__ float Ws[64 * SW];

    const int t = threadIdx.x;
    const int row0 = blockIdx.x * 64;
    const int r0 = 4 * (t >> 4), n0 = 4 * (t & 15);
    const int rgm = (t >> 5) & 3;

    float4 aR[4], wR[4];
    loadA4(aR, X, row0, M, 64, 0, t);
    loadW4(wR, W, 64, 0, t);
    writeA4(As, aR, t);
    writeW4(Ws, wR, t);
    __syncthreads();

    float acc[4][4] = {};
    gemm_4x4(As, Ws, r0, n0, rgm, acc);

    float bv[4] = { bias[n0], bias[n0 + 1], bias[n0 + 2], bias[n0 + 3] };
#pragma unroll
    for (int j = 0; j < 4; ++j) {
        int gr = row0 + r0 + j;
        if (gr < M) {
            float4 v = make_float4(acc[j][0] + bv[0], acc[j][1] + bv[1],
                                   acc[j][2] + bv[2], acc[j][3] + bv[3]);
            *(float4*)&Y[(size_t)gr * HH + n0] = v;
        }
    }
}

// ---------------------------------------------------------------------------
// CSR build
// ---------------------------------------------------------------------------
__global__ __launch_bounds__(256)
void zero_int_kernel(int* __restrict__ p, int n)
{
    for (int i = blockIdx.x * 256 + threadIdx.x; i < n; i += gridDim.x * 256)
        p[i] = 0;
}

__global__ __launch_bounds__(256)
void scan_blocks_kernel(const int* __restrict__ counts, int* __restrict__ ex,
                        int* __restrict__ bsum)
{
    __shared__ int wtot[4];
    int t = threadIdx.x;
    int base = blockIdx.x * 1024 + t * 4;
    int v0 = 0, v1 = 0, v2 = 0, v3 = 0;
    if (base + 3 < N_NODES) {
        int4 c = *reinterpret_cast<const int4*>(&counts[base]);
        v0 = c.x; v1 = c.y; v2 = c.z; v3 = c.w;
    } else {
        if (base + 0 < N_NODES) v0 = counts[base + 0];
        if (base + 1 < N_NODES) v1 = counts[base + 1];
        if (base + 2 < N_NODES) v2 = counts[base + 2];
        if (base + 3 < N_NODES) v3 = counts[base + 3];
    }
    int s1 = v0 + v1, s2 = s1 + v2, tot = s2 + v3;
    int inc = tot;
#pragma unroll
    for (int d = 1; d < 64; d <<= 1) {
        int u = __shfl_up(inc, d);
        if ((t & 63) >= d) inc += u;
    }
    if ((t & 63) == 63) wtot[t >> 6] = inc;
    __syncthreads();
    int w = t >> 6;
    int woff = 0;
#pragma unroll
    for (int i = 0; i < 4; ++i)
        if (i < w) woff += wtot[i];
    int ex0 = woff + inc - tot;
    if (base + 0 < N_NODES) ex[base + 0] = ex0;
    if (base + 1 < N_NODES) ex[base + 1] = ex0 + v0;
    if (base + 2 < N_NODES) ex[base + 2] = ex0 + s1;
    if (base + 3 < N_NODES) ex[base + 3] = ex0 + s2;
    if (t == 255) bsum[blockIdx.x] = woff + inc;
}

// finalize: row_ptr[i] += prefix(bsum[0..block)), cursor = row_ptr
__global__ __launch_bounds__(256)
void finalize_kernel(int* __restrict__ row_ptr, const int* __restrict__ bsum,
                     int* __restrict__ cursor)
{
    __shared__ int ws[4];
    int t = threadIdx.x;
    int part = (t < (int)blockIdx.x) ? bsum[t] : 0;   // SCAN_NBLK <= 256
#pragma unroll
    for (int d = 1; d < 64; d <<= 1) part += __shfl_xor(part, d);
    if ((t & 63) == 0) ws[t >> 6] = part;
    __syncthreads();
    int prefix = ws[0] + ws[1] + ws[2] + ws[3];
    int base = blockIdx.x * 1024 + t * 4;
#pragma unroll
    for (int u = 0; u < 4; ++u) {
        int i = base + u;
        if (i < N_NODES) {
            int v = row_ptr[i] + prefix;
            row_ptr[i] = v;
            cursor[i] = v;
        }
    }
    if (blockIdx.x == 0 && t == 0) row_ptr[N_NODES] = NEDGES;
}

__global__ __launch_bounds__(256)
void scatter_kernel(const int* __restrict__ rows, const int* __restrict__ cols,
                    const float* __restrict__ vals, int* __restrict__ cursor,
                    int2* __restrict__ edges)
{
    int e = blockIdx.x * 256 + threadIdx.x;
    if (e < NEDGES) {
        int r = rows[e];
        int p = atomicAdd(&cursor[r], 1);
        edges[p] = make_int2(cols[e], __float_as_int(vals[e]));
    }
}

// ---------------------------------------------------------------------------
// CSR SPMM: 32 rows/block, 16 lanes per row, TWO rows per lane group ->
// 8 independent loads in flight per lane (2 int2 + 2 gathers per row per
// joint iteration). Fused relu + z-accumulate.
// ---------------------------------------------------------------------------
__global__ __launch_bounds__(256)
void spmm_csr_kernel(const int* __restrict__ row_ptr, const int2* __restrict__ edges,
                     const float* __restrict__ Xin,
                     float* __restrict__ A, float* __restrict__ z,
                     int dorelu, int writeA)
{
    int t = threadIdx.x;
    int g = t >> 4;
    int q = (t & 15) * 4;
    int ra = blockIdx.x * 32 + g;
    if (ra >= N_NODES) return;
    int rb = ra + 16;
    bool hasB = rb < N_NODES;

    int e0 = row_ptr[ra], end0 = row_ptr[ra + 1];
    int e1 = 0, end1 = 0;
    if (hasB) { e1 = row_ptr[rb]; end1 = row_ptr[rb + 1]; }

    float4 acc0 = make_float4(0.f, 0.f, 0.f, 0.f);
    float4 acc1 = make_float4(0.f, 0.f, 0.f, 0.f);

    // joint loop: 2 edges per row per iteration (8 loads in flight)
    while (e0 + 1 < end0 && e1 + 1 < end1) {
        int2 pa0 = edges[e0], pa1 = edges[e0 + 1];
        int2 pb0 = edges[e1], pb1 = edges[e1 + 1];
        float4 xa0 = *reinterpret_cast<const float4*>(&Xin[(size_t)pa0.x * HH + q]);
        float4 xa1 = *reinterpret_cast<const float4*>(&Xin[(size_t)pa1.x * HH + q]);
        float4 xb0 = *reinterpret_cast<const float4*>(&Xin[(size_t)pb0.x * HH + q]);
        float4 xb1 = *reinterpret_cast<const float4*>(&Xin[(size_t)pb1.x * HH + q]);
        float va0 = __int_as_float(pa0.y), va1 = __int_as_float(pa1.y);
        float vb0 = __int_as_float(pb0.y), vb1 = __int_as_float(pb1.y);
        acc0.x += va0 * xa0.x; acc0.y += va0 * xa0.y; acc0.z += va0 * xa0.z; acc0.w += va0 * xa0.w;
        acc0.x += va1 * xa1.x; acc0.y += va1 * xa1.y; acc0.z += va1 * xa1.z; acc0.w += va1 * xa1.w;
        acc1.x += vb0 * xb0.x; acc1.y += vb0 * xb0.y; acc1.z += vb0 * xb0.z; acc1.w += vb0 * xb0.w;
        acc1.x += vb1 * xb1.x; acc1.y += vb1 * xb1.y; acc1.z += vb1 * xb1.z; acc1.w += vb1 * xb1.w;
        e0 += 2; e1 += 2;
    }
    // drain row a
    for (; e0 + 1 < end0; e0 += 2) {
        int2 p0 = edges[e0], p1 = edges[e0 + 1];
        float4 x0 = *reinterpret_cast<const float4*>(&Xin[(size_t)p0.x * HH + q]);
        float4 x1 = *reinterpret_cast<const float4*>(&Xin[(size_t)p1.x * HH + q]);
        float v0 = __int_as_float(p0.y), v1 = __int_as_float(p1.y);
        acc0.x += v0 * x0.x; acc0.y += v0 * x0.y; acc0.z += v0 * x0.z; acc0.w += v0 * x0.w;
        acc0.x += v1 * x1.x; acc0.y += v1 * x1.y; acc0.z += v1 * x1.z; acc0.w += v1 * x1.w;
    }
    if (e0 < end0) {
        int2 p = edges[e0];
        float v = __int_as_float(p.y);
        float4 x = *reinterpret_cast<const float4*>(&Xin[(size_t)p.x * HH + q]);
        acc0.x += v * x.x; acc0.y += v * x.y; acc0.z += v * x.z; acc0.w += v * x.w;
    }
    // drain row b
    for (; e1 + 1 < end1; e1 += 2) {
        int2 p0 = edges[e1], p1 = edges[e1 + 1];
        float4 x0 = *reinterpret_cast<const float4*>(&Xin[(size_t)p0.x * HH + q]);
        float4 x1 = *reinterpret_cast<const float4*>(&Xin[(size_t)p1.x * HH + q]);
        float v0 = __int_as_float(p0.y), v1 = __int_as_float(p1.y);
        acc1.x += v0 * x0.x; acc1.y += v0 * x0.y; acc1.z += v0 * x0.z; acc1.w += v0 * x0.w;
        acc1.x += v1 * x1.x; acc1.y += v1 * x1.y; acc1.z += v1 * x1.z; acc1.w += v1 * x1.w;
    }
    if (e1 < end1) {
        int2 p = edges[e1];
        float v = __int_as_float(p.y);
        float4 x = *reinterpret_cast<const float4*>(&Xin[(size_t)p.x * HH + q]);
        acc1.x += v * x.x; acc1.y += v * x.y; acc1.z += v * x.z; acc1.w += v * x.w;
    }

    if (dorelu) {
        acc0.x = fmaxf(acc0.x, 0.f); acc0.y = fmaxf(acc0.y, 0.f);
        acc0.z = fmaxf(acc0.z, 0.f); acc0.w = fmaxf(acc0.w, 0.f);
        acc1.x = fmaxf(acc1.x, 0.f); acc1.y = fmaxf(acc1.y, 0.f);
        acc1.z = fmaxf(acc1.z, 0.f); acc1.w = fmaxf(acc1.w, 0.f);
    }
    size_t oa = (size_t)ra * HH + q;
    if (writeA) *reinterpret_cast<float4*>(&A[oa]) = acc0;
    float4 za = *reinterpret_cast<float4*>(&z[oa]);
    za.x += acc0.x; za.y += acc0.y; za.z += acc0.z; za.w += acc0.w;
    *reinterpret_cast<float4*>(&z[oa]) = za;
    if (hasB) {
        size_t ob = (size_t)rb * HH + q;
        if (writeA) *reinterpret_cast<float4*>(&A[ob]) = acc1;
        float4 zb = *reinterpret_cast<float4*>(&z[ob]);
        zb.x += acc1.x; zb.y += acc1.y; zb.z += acc1.z; zb.w += acc1.w;
        *reinterpret_cast<float4*>(&z[ob]) = zb;
    }
}

// ---------------------------------------------------------------------------
// Scorer: 32 queries per block, K=256 GEMM in 4 chunks of 64 with
// issue-early W preloading; float4 W staging.
// ---------------------------------------------------------------------------
#define SAs 268
#define SWs 68

__device__ __forceinline__ void loadWs(float4 wS[4], const float* __restrict__ W,
                                       int koff, int t)
{
#pragma unroll
    for (int i = 0; i < 4; ++i) {
        int idx = t + i * 256;
        int n = idx & 63, k4 = idx >> 6;
        wS[i] = *(const float4*)&W[(size_t)n * 256 + koff + k4 * 4];
    }
}

__device__ __forceinline__ void writeWs(float* __restrict__ Ws2, const float4 wS[4], int t)
{
#pragma unroll
    for (int i = 0; i < 4; ++i) {
        int idx = t + i * 256;
        int n = idx & 63, k4 = idx >> 6;
        Ws2[(k4 * 4 + 0) * SWs + n] = wS[i].x;
        Ws2[(k4 * 4 + 1) * SWs + n] = wS[i].y;
        Ws2[(k4 * 4 + 2) * SWs + n] = wS[i].z;
        Ws2[(k4 * 4 + 3) * SWs + n] = wS[i].w;
    }
}

__global__ __launch_bounds__(256)
void scorer_kernel(const float* __restrict__ z, const int* __restrict__ uidx,
                   const int* __restrict__ iidx,
                   const float* __restrict__ s1W, const float* __restrict__ s1b,
                   const float* __restrict__ s2W, const float* __restrict__ s2b,
                   const float* __restrict__ ubias, const float* __restrict__ ibias,
                   const float* __restrict__ gmean, float* __restrict__ out)
{
    __shared__ float As2[32 * SAs];  // 34.3 KB
    __shared__ float Ws2[64 * SWs];  // 17.4 KB

    const int t = threadIdx.x;
    const int row0 = blockIdx.x * 32;
    const int r0 = 2 * (t >> 4);
    const int n0 = 4 * (t & 15);

#pragma unroll
    for (int i = 0; i < 4; ++i) {
        int idx = t + i * 256;
        int half = idx >> 9;
        int rid = idx & 511;
        int r = rid >> 4, c4 = rid & 15;
        int q = row0 + r;
        int node = half ? (N_USERS + iidx[q]) : uidx[q];
        float4 v = *(const float4*)&z[(size_t)node * HH + c4 * 4];
        v.x *= (1.f / 3.f); v.y *= (1.f / 3.f); v.z *= (1.f / 3.f); v.w *= (1.f / 3.f);
        *(float4*)&As2[r * SAs + half * 64 + c4 * 4] = v;
    }
    float4 wS[4];
    loadWs(wS, s1W, 0, t);
    __syncthreads();
#pragma unroll
    for (int i = 0; i < 2; ++i) {
        int idx = t + i * 256;
        int r = idx >> 4, c4 = idx & 15;
        float4 a = *(const float4*)&As2[r * SAs + c4 * 4];
        float4 b = *(const float4*)&As2[r * SAs + 64 + c4 * 4];
        float4 p, d;
        p.x = a.x * b.x; p.y = a.y * b.y; p.z = a.z * b.z; p.w = a.w * b.w;
        d.x = fabsf(a.x - b.x); d.y = fabsf(a.y - b.y);
        d.z = fabsf(a.z - b.z); d.w = fabsf(a.w - b.w);
        *(float4*)&As2[r * SAs + 128 + c4 * 4] = p;
        *(float4*)&As2[r * SAs + 192 + c4 * 4] = d;
    }
    writeWs(Ws2, wS, t);
    __syncthreads();

    float acc[2][4] = {};
#pragma unroll
    for (int c = 0; c < 4; ++c) {
        if (c < 3) loadWs(wS, s1W, (c + 1) * 64, t);
#pragma unroll 2
        for (int k0 = 0; k0 < 64; k0 += 4) {
            float4 a0 = *(const float4*)&As2[(r0 + 0) * SAs + c * 64 + k0];
            float4 a1 = *(const float4*)&As2[(r0 + 1) * SAs + c * 64 + k0];
            float4 w[4];
            w[0] = *(const float4*)&Ws2[(k0 + 0) * SWs + n0];
            w[1] = *(const float4*)&Ws2[(k0 + 1) * SWs + n0];
            w[2] = *(const float4*)&Ws2[(k0 + 2) * SWs + n0];
            w[3] = *(const float4*)&Ws2[(k0 + 3) * SWs + n0];
            float av0[4] = { a0.x, a0.y, a0.z, a0.w };
            float av1[4] = { a1.x, a1.y, a1.z, a1.w };
#pragma unroll
            for (int kk = 0; kk < 4; ++kk) {
                acc[0][0] += av0[kk] * (&w[kk].x)[0];
                acc[0][1] += av0[kk] * (&w[kk].x)[1];
                acc[0][2] += av0[kk] * (&w[kk].x)[2];
                acc[0][3] += av0[kk] * (&w[kk].x)[3];
                acc[1][0] += av1[kk] * (&w[kk].x)[0];
                acc[1][1] += av1[kk] * (&w[kk].x)[1];
                acc[1][2] += av1[kk] * (&w[kk].x)[2];
                acc[1][3] += av1[kk] * (&w[kk].x)[3];
            }
        }
        __syncthreads();
        if (c < 3) {
            writeWs(Ws2, wS, t);
            __syncthreads();
        }
    }

    float b1v[4] = { s1b[n0], s1b[n0 + 1], s1b[n0 + 2], s1b[n0 + 3] };
    float s2w[4] = { s2W[n0], s2W[n0 + 1], s2W[n0 + 2], s2W[n0 + 3] };
    float pj[2];
#pragma unroll
    for (int j = 0; j < 2; ++j) {
        float p = 0.f;
#pragma unroll
        for (int i = 0; i < 4; ++i)
            p += fmaxf(acc[j][i] + b1v[i], 0.f) * s2w[i];
        p += __shfl_xor(p, 1); p += __shfl_xor(p, 2);
        p += __shfl_xor(p, 4); p += __shfl_xor(p, 8);
        pj[j] = p;
    }
    if ((t & 15) == 0) {
        float gm = gmean[0], b2 = s2b[0];
#pragma unroll
        for (int j = 0; j < 2; ++j) {
            int q = row0 + r0 + j;
            float pred = gm + ubias[uidx[q]] + ibias[iidx[q]] + b2 + pj[j];
            pred = fminf(fmaxf(pred, 1.f), 5.f);
            out[q] = pred;
        }
    }
}

// ---------------------------------------------------------------------------
extern "C" void kernel_launch(void* const* d_in, const int* in_sizes, int n_in,
                              void* d_out, int out_size, void* d_ws, size_t ws_size,
                              hipStream_t stream)
{
    const float* user_feat = (const float*)d_in[0];
    const float* item_feat = (const float*)d_in[1];
    const float* adj_vals  = (const float*)d_in[2];
    const float* ue_W  = (const float*)d_in[3];
    const float* ue_b  = (const float*)d_in[4];
    const float* ue_g  = (const float*)d_in[5];
    const float* ue_be = (const float*)d_in[6];
    const float* ie_W  = (const float*)d_in[7];
    const float* ie_b  = (const float*)d_in[8];
    const float* ie_g  = (const float*)d_in[9];
    const float* ie_be = (const float*)d_in[10];
    const float* uid_emb = (const float*)d_in[11];
    const float* iid_emb = (const float*)d_in[12];
    const float* uf_W  = (const float*)d_in[13];
    const float* uf_b  = (const float*)d_in[14];
    const float* uf_g  = (const float*)d_in[15];
    const float* uf_be = (const float*)d_in[16];
    const float* if_W  = (const float*)d_in[17];
    const float* if_b  = (const float*)d_in[18];
    const float* if_g  = (const float*)d_in[19];
    const float* if_be = (const float*)d_in[20];
    const float* gcn_W = (const float*)d_in[21];
    const float* gcn_b = (const float*)d_in[22];
    const float* ubias = (const float*)d_in[23];
    const float* ibias = (const float*)d_in[24];
    const float* s1_W  = (const float*)d_in[25];
    const float* s1_b  = (const float*)d_in[26];
    const float* s2_W  = (const float*)d_in[27];
    const float* s2_b  = (const float*)d_in[28];
    const float* gmean = (const float*)d_in[29];
    const int* adj_rows = (const int*)d_in[30];
    const int* adj_cols = (const int*)d_in[31];
    const int* user_idx = (const int*)d_in[32];
    const int* item_idx = (const int*)d_in[33];
    float* out = (float*)d_out;

    float* z = (float*)d_ws;                       // [N*64]
    float* A = z + (size_t)N_NODES * HH;           // [N*64]
    float* B = A + (size_t)N_NODES * HH;           // [N*64]
    int2* edges = (int2*)(B + (size_t)N_NODES * HH); // [E] packed (col,val)
    int* row_ptr = (int*)(edges + NEDGES);         // [N+1]
    int* cursor  = row_ptr + N_NODES + 4;          // [N] (histogram + cursors)
    int* bsum    = cursor + N_NODES;               // [SCAN_NBLK]

    const int ublocks = (N_USERS + 63) / 64;       // 1563
    const int iblocks = (N_ITEMS + 63) / 64;       // 782
    const int encB = ublocks + iblocks;            // 2345
    const int nblocks = (N_NODES + 63) / 64;       // 2344
    const int eblocks = (NEDGES + 255) / 256;      // 4688

    // ---- 1. zero histogram ----
    zero_int_kernel<<<512, 256, 0, stream>>>(cursor, N_NODES);

    // ---- 2. encoder (+gcn-L1 fused) || histogram ----
    encode_hist_kernel<<<encB + eblocks, 256, 0, stream>>>(
        ublocks, encB,
        user_feat, item_feat, ue_W, ie_W, ue_b, ie_b, ue_g, ie_g, ue_be, ie_be,
        uid_emb, iid_emb, uf_W, if_W, uf_b, if_b, uf_g, if_g, uf_be, if_be,
        gcn_W, gcn_b, z, B, adj_rows, cursor);

    // ---- 3-5. CSR scan / finalize / scatter ----
    scan_blocks_kernel<<<SCAN_NBLK, 256, 0, stream>>>(cursor, row_ptr, bsum);
    finalize_kernel<<<SCAN_NBLK, 256, 0, stream>>>(row_ptr, bsum, cursor);
    scatter_kernel<<<eblocks, 256, 0, stream>>>(adj_rows, adj_cols, adj_vals,
                                                cursor, edges);

    // ---- 6. spmm layer 1: x1 = relu(spmm(B1)); A = x1; z += x1 ----
    const int sblocks = (N_NODES + 31) / 32;
    spmm_csr_kernel<<<sblocks, 256, 0, stream>>>(row_ptr, edges, B, A, z, 1, 1);

    // ---- 7. linear L2: B2 = A @ gW1.T + gb1 ----
    linear64_kernel<<<nblocks, 256, 0, stream>>>(
        A, gcn_W + HH * HH, gcn_b + HH, B, N_NODES);

    // ---- 8. spmm layer 2: z += spmm(B2) ----
    spmm_csr_kernel<<<sblocks, 256, 0, stream>>>(row_ptr, edges, B, A, z, 0, 0);

    // ---- 9. scorer ----
    scorer_kernel<<<NQ / 32, 256, 0, stream>>>(
        z, user_idx, item_idx, s1_W, s1_b, s2_W, s2_b, ubias, ibias, gmean, out);
}

// Round 11
// 513.458 us; speedup vs baseline: 1.0417x; 1.0417x over previous
//
#include <hip/hip_runtime.h>

#define N_USERS 100000
#define N_ITEMS 50000
#define N_NODES 150000
#define HH 64
#define NEDGES 1200000
#define NQ 16384
#define LN_EPS 1e-5f
#define SCAN_NBLK 147   // ceil(150000/1024)

// ---------------------------------------------------------------------------
// GEMM micro-tile: 64 rows x 64 cols per block, 256 threads, 4x4 per thread.
// As[r][68] row-major, k-chunk position XOR-swizzled by (r>>3)&3.
// Staging split into load(regs)/write(LDS): next-phase global loads issued
// BEFORE the current gemm so they complete under it.
// ---------------------------------------------------------------------------
#define SA 68
#define SW 68

__device__ __forceinline__ void loadA4(float4 aR[4], const float* __restrict__ src,
                                       int row0, int M, int stride, int koff, int t)
{
#pragma unroll
    for (int i = 0; i < 4; ++i) {
        int f4 = t + i * 256;              // 64 rows x 16 float4
        int r = f4 >> 4, k4 = f4 & 15;
        int gr = row0 + r;
        aR[i] = make_float4(0.f, 0.f, 0.f, 0.f);
        if (gr < M) aR[i] = *(const float4*)&src[(size_t)gr * stride + koff + k4 * 4];
    }
}

__device__ __forceinline__ void writeA4(float* __restrict__ As, const float4 aR[4], int t)
{
#pragma unroll
    for (int i = 0; i < 4; ++i) {
        int f4 = t + i * 256;
        int r = f4 >> 4, k4 = f4 & 15;
        *(float4*)&As[r * SA + ((k4 ^ ((r >> 3) & 3)) << 2)] = aR[i];
    }
}

__device__ __forceinline__ void loadW4(float4 wR[4], const float* __restrict__ W,
                                       int KW, int koff, int t)
{
#pragma unroll
    for (int i = 0; i < 4; ++i) {
        int idx = t + i * 256;
        int n = idx & 63, k4 = idx >> 6;
        wR[i] = *(const float4*)&W[(size_t)n * KW + koff + k4 * 4];
    }
}

__device__ __forceinline__ void writeW4(float* __restrict__ Ws, const float4 wR[4], int t)
{
#pragma unroll
    for (int i = 0; i < 4; ++i) {
        int idx = t + i * 256;
        int n = idx & 63, k4 = idx >> 6;
        Ws[(k4 * 4 + 0) * SW + n] = wR[i].x;
        Ws[(k4 * 4 + 1) * SW + n] = wR[i].y;
        Ws[(k4 * 4 + 2) * SW + n] = wR[i].z;
        Ws[(k4 * 4 + 3) * SW + n] = wR[i].w;
    }
}

__device__ __forceinline__ void gemm_4x4(const float* __restrict__ As,
                                         const float* __restrict__ Ws,
                                         int r0, int n0, int rgm, float acc[4][4])
{
#pragma unroll 4
    for (int k4c = 0; k4c < 16; ++k4c) {
        int aoff = ((k4c ^ rgm) << 2);
        float4 a[4], w[4];
#pragma unroll
        for (int j = 0; j < 4; ++j)
            a[j] = *(const float4*)&As[(r0 + j) * SA + aoff];
#pragma unroll
        for (int kk = 0; kk < 4; ++kk)
            w[kk] = *(const float4*)&Ws[(k4c * 4 + kk) * SW + n0];
#pragma unroll
        for (int j = 0; j < 4; ++j) {
            float av[4] = { a[j].x, a[j].y, a[j].z, a[j].w };
#pragma unroll
            for (int kk = 0; kk < 4; ++kk) {
                acc[j][0] += av[kk] * (&w[kk].x)[0];
                acc[j][1] += av[kk] * (&w[kk].x)[1];
                acc[j][2] += av[kk] * (&w[kk].x)[2];
                acc[j][3] += av[kk] * (&w[kk].x)[3];
            }
        }
    }
}

// bias+ReLU+LayerNorm for 4 rows x 4 cols; row's 64 cols live in 16 lanes.
__device__ __forceinline__ void relu_ln44(const float acc[4][4], float y[4][4],
                                          const float* __restrict__ bias,
                                          const float* __restrict__ g,
                                          const float* __restrict__ be, int n0)
{
    float bv[4] = { bias[n0], bias[n0 + 1], bias[n0 + 2], bias[n0 + 3] };
    float gv[4] = { g[n0], g[n0 + 1], g[n0 + 2], g[n0 + 3] };
    float bev[4] = { be[n0], be[n0 + 1], be[n0 + 2], be[n0 + 3] };
#pragma unroll
    for (int j = 0; j < 4; ++j) {
        float yj[4];
#pragma unroll
        for (int i = 0; i < 4; ++i)
            yj[i] = fmaxf(acc[j][i] + bv[i], 0.f);
        float s = yj[0] + yj[1] + yj[2] + yj[3];
        s += __shfl_xor(s, 1); s += __shfl_xor(s, 2);
        s += __shfl_xor(s, 4); s += __shfl_xor(s, 8);
        float mean = s * (1.f / 64.f);
        float d0 = yj[0] - mean, d1 = yj[1] - mean;
        float d2 = yj[2] - mean, d3 = yj[3] - mean;
        float q = d0 * d0 + d1 * d1 + d2 * d2 + d3 * d3;
        q += __shfl_xor(q, 1); q += __shfl_xor(q, 2);
        q += __shfl_xor(q, 4); q += __shfl_xor(q, 8);
        float inv = rsqrtf(q * (1.f / 64.f) + LN_EPS);
#pragma unroll
        for (int i = 0; i < 4; ++i)
            y[j][i] = (yj[i] - mean) * inv * gv[i] + bev[i];
    }
}

// ---------------------------------------------------------------------------
// Mega-kernel with INTERLEAVED roles: bid%3==0 -> encoder block (bid/3);
// else -> histogram block. Interleaving makes latency-bound hist blocks
// co-resident with VALU-bound encode blocks (round 10 ran hist as a tail).
// Encoder: enc = LN(relu(feat@W1.T+b1)); x0 = LN(relu([enc|emb]@W2.T+b2));
//          z = x0;  B1 = x0 @ gW0.T + gb0.
// ---------------------------------------------------------------------------
__global__ __launch_bounds__(256)
void encode_hist_kernel(int ublocks,
                        const float* __restrict__ ufeat, const float* __restrict__ ifeat,
                        const float* __restrict__ uW1, const float* __restrict__ iW1,
                        const float* __restrict__ ub1, const float* __restrict__ ib1,
                        const float* __restrict__ ug1, const float* __restrict__ ig1,
                        const float* __restrict__ ube1, const float* __restrict__ ibe1,
                        const float* __restrict__ uemb, const float* __restrict__ iemb,
                        const float* __restrict__ uW2, const float* __restrict__ iW2,
                        const float* __restrict__ ub2, const float* __restrict__ ib2,
                        const float* __restrict__ ug2, const float* __restrict__ ig2,
                        const float* __restrict__ ube2, const float* __restrict__ ibe2,
                        const float* __restrict__ gW0, const float* __restrict__ gb0,
                        float* __restrict__ z, float* __restrict__ B1,
                        const int* __restrict__ adj_rows, int* __restrict__ counts)
{
    const int bid = blockIdx.x;
    const int t = threadIdx.x;
    const int role = bid % 3;

    // ---- histogram role (2 of every 3 blocks) ----
    if (role) {
        int hb = (bid / 3) * 2 + (role - 1);
        int e = hb * 256 + t;
        if (e < NEDGES) atomicAdd(&counts[adj_rows[e]], 1);
        return;
    }
    const int eb = bid / 3;   // encoder block index, 0..ublocks+iblocks-1

    __shared__ float As[64 * SA];   // 17.4 KB
    __shared__ float Ws[64 * SW];   // 17.4 KB

    const bool isU = eb < ublocks;
    const float* feat = isU ? ufeat : ifeat;
    const float* W1 = isU ? uW1 : iW1;
    const float* b1 = isU ? ub1 : ib1;
    const float* g1 = isU ? ug1 : ig1;
    const float* be1 = isU ? ube1 : ibe1;
    const float* emb = isU ? uemb : iemb;
    const float* W2 = isU ? uW2 : iW2;
    const float* b2 = isU ? ub2 : ib2;
    const float* g2 = isU ? ug2 : ig2;
    const float* be2 = isU ? ube2 : ibe2;
    const int M = isU ? N_USERS : N_ITEMS;
    const int yoff = isU ? 0 : N_USERS;
    const int row0 = (isU ? eb : eb - ublocks) * 64;

    const int cg = t & 15;
    const int r0 = 4 * (t >> 4), n0 = cg * 4;
    const int rgm = (t >> 5) & 3;   // == ((r0>>3)&3), constant over r0..r0+3

    float4 aR[4], wR[4];

    // ---- P0 stage: feat c0, W1 c0 ----
    loadA4(aR, feat, row0, M, 128, 0, t);
    loadW4(wR, W1, 128, 0, t);
    writeA4(As, aR, t);
    writeW4(Ws, wR, t);
    __syncthreads();

    // ---- P0 body: issue P1 loads, gemm P0 ----
    float acc[4][4] = {};
    loadA4(aR, feat, row0, M, 128, 64, t);
    loadW4(wR, W1, 128, 64, t);
    gemm_4x4(As, Ws, r0, n0, rgm, acc);
    __syncthreads();
    writeA4(As, aR, t);
    writeW4(Ws, wR, t);
    __syncthreads();

    // ---- P1 body: issue P2 loads (W2 c0), gemm P1, relu+LN ----
    loadW4(wR, W2, 128, 0, t);
    gemm_4x4(As, Ws, r0, n0, rgm, acc);
    float y[4][4];
    relu_ln44(acc, y, b1, g1, be1, n0);
    __syncthreads();
    // P2 stage: enc y -> As (swizzled), W2 c0 -> Ws
#pragma unroll
    for (int i = 0; i < 4; ++i)
#pragma unroll
        for (int j = 0; j < 4; ++j)
            As[(r0 + j) * SA + ((cg ^ rgm) << 2) + i] = y[j][i];
    writeW4(Ws, wR, t);
    __syncthreads();

    // ---- P2 body: issue P3 loads (emb, W2 c1), gemm P2 ----
    float acc2[4][4] = {};
    loadA4(aR, emb, row0, M, 64, 0, t);
    loadW4(wR, W2, 128, 64, t);
    gemm_4x4(As, Ws, r0, n0, rgm, acc2);
    __syncthreads();
    writeA4(As, aR, t);
    writeW4(Ws, wR, t);
    __syncthreads();

    // ---- P3 body: issue P4 loads (gcn W0), gemm P3, relu+LN -> x0 ----
    loadW4(wR, gW0, 64, 0, t);
    gemm_4x4(As, Ws, r0, n0, rgm, acc2);
    float y2[4][4];
    relu_ln44(acc2, y2, b2, g2, be2, n0);
    // write z = x0
#pragma unroll
    for (int j = 0; j < 4; ++j) {
        int gr = row0 + r0 + j;
        if (gr < M)
            *(float4*)&z[(size_t)(yoff + gr) * HH + n0] =
                make_float4(y2[j][0], y2[j][1], y2[j][2], y2[j][3]);
    }
    __syncthreads();
    // P4 stage: x0 -> As, gW0 -> Ws
#pragma unroll
    for (int i = 0; i < 4; ++i)
#pragma unroll
        for (int j = 0; j < 4; ++j)
            As[(r0 + j) * SA + ((cg ^ rgm) << 2) + i] = y2[j][i];
    writeW4(Ws, wR, t);
    __syncthreads();

    // ---- P4 body: gemm L1, add gcn bias, write B1 ----
    float acc3[4][4] = {};
    gemm_4x4(As, Ws, r0, n0, rgm, acc3);
    float gbv[4] = { gb0[n0], gb0[n0 + 1], gb0[n0 + 2], gb0[n0 + 3] };
#pragma unroll
    for (int j = 0; j < 4; ++j) {
        int gr = row0 + r0 + j;
        if (gr < M)
            *(float4*)&B1[(size_t)(yoff + gr) * HH + n0] =
                make_float4(acc3[j][0] + gbv[0], acc3[j][1] + gbv[1],
                            acc3[j][2] + gbv[2], acc3[j][3] + gbv[3]);
    }
}

// ---------------------------------------------------------------------------
// GCN linear (layer 2 only): Y = X@W.T + b, K=64, 64-row blocks.
// ---------------------------------------------------------------------------
__global__ __launch_bounds__(256)
void linear64_kernel(const float* __restrict__ X, const float* __restrict__ W,
                     const float* __restrict__ bias, float* __restrict__ Y, int M)
{
    __shared__ float As[64 * SA];
    __shared__ float Ws[64 * SW];

    const int t = threadIdx.x;
    const int row0 = blockIdx.x * 64;
    const int r0 = 4 * (t >> 4), n0 = 4 * (t & 15);
    const int rgm = (t >> 5) & 3;

    float4 aR[4], wR[4];
    loadA4(aR, X, row0, M, 64, 0, t);
    loadW4(wR, W, 64, 0, t);
    writeA4(As, aR, t);
    writeW4(Ws, wR, t);
    __syncthreads();

    float acc[4][4] = {};
    gemm_4x4(As, Ws, r0, n0, rgm, acc);

    float bv[4] = { bias[n0], bias[n0 + 1], bias[n0 + 2], bias[n0 + 3] };
#pragma unroll
    for (int j = 0; j < 4; ++j) {
        int gr = row0 + r0 + j;
        if (gr < M) {
            float4 v = make_float4(acc[j][0] + bv[0], acc[j][1] + bv[1],
                                   acc[j][2] + bv[2], acc[j][3] + bv[3]);
            *(float4*)&Y[(size_t)gr * HH + n0] = v;
        }
    }
}

// ---------------------------------------------------------------------------
// CSR build
// ---------------------------------------------------------------------------
__global__ __launch_bounds__(256)
void zero_int_kernel(int* __restrict__ p, int n)
{
    for (int i = blockIdx.x * 256 + threadIdx.x; i < n; i += gridDim.x * 256)
        p[i] = 0;
}

__global__ __launch_bounds__(256)
void scan_blocks_kernel(const int* __restrict__ counts, int* __restrict__ ex,
                        int* __restrict__ bsum)
{
    __shared__ int wtot[4];
    int t = threadIdx.x;
    int base = blockIdx.x * 1024 + t * 4;
    int v0 = 0, v1 = 0, v2 = 0, v3 = 0;
    if (base + 3 < N_NODES) {
        int4 c = *reinterpret_cast<const int4*>(&counts[base]);
        v0 = c.x; v1 = c.y; v2 = c.z; v3 = c.w;
    } else {
        if (base + 0 < N_NODES) v0 = counts[base + 0];
        if (base + 1 < N_NODES) v1 = counts[base + 1];
        if (base + 2 < N_NODES) v2 = counts[base + 2];
        if (base + 3 < N_NODES) v3 = counts[base + 3];
    }
    int s1 = v0 + v1, s2 = s1 + v2, tot = s2 + v3;
    int inc = tot;
#pragma unroll
    for (int d = 1; d < 64; d <<= 1) {
        int u = __shfl_up(inc, d);
        if ((t & 63) >= d) inc += u;
    }
    if ((t & 63) == 63) wtot[t >> 6] = inc;
    __syncthreads();
    int w = t >> 6;
    int woff = 0;
#pragma unroll
    for (int i = 0; i < 4; ++i)
        if (i < w) woff += wtot[i];
    int ex0 = woff + inc - tot;
    if (base + 0 < N_NODES) ex[base + 0] = ex0;
    if (base + 1 < N_NODES) ex[base + 1] = ex0 + v0;
    if (base + 2 < N_NODES) ex[base + 2] = ex0 + s1;
    if (base + 3 < N_NODES) ex[base + 3] = ex0 + s2;
    if (t == 255) bsum[blockIdx.x] = woff + inc;
}

// finalize: row_ptr[i] += prefix(bsum[0..block)), cursor = row_ptr
__global__ __launch_bounds__(256)
void finalize_kernel(int* __restrict__ row_ptr, const int* __restrict__ bsum,
                     int* __restrict__ cursor)
{
    __shared__ int ws[4];
    int t = threadIdx.x;
    int part = (t < (int)blockIdx.x) ? bsum[t] : 0;   // SCAN_NBLK <= 256
#pragma unroll
    for (int d = 1; d < 64; d <<= 1) part += __shfl_xor(part, d);
    if ((t & 63) == 0) ws[t >> 6] = part;
    __syncthreads();
    int prefix = ws[0] + ws[1] + ws[2] + ws[3];
    int base = blockIdx.x * 1024 + t * 4;
#pragma unroll
    for (int u = 0; u < 4; ++u) {
        int i = base + u;
        if (i < N_NODES) {
            int v = row_ptr[i] + prefix;
            row_ptr[i] = v;
            cursor[i] = v;
        }
    }
    if (blockIdx.x == 0 && t == 0) row_ptr[N_NODES] = NEDGES;
}

__global__ __launch_bounds__(256)
void scatter_kernel(const int* __restrict__ rows, const int* __restrict__ cols,
                    const float* __restrict__ vals, int* __restrict__ cursor,
                    int2* __restrict__ edges)
{
    int e = blockIdx.x * 256 + threadIdx.x;
    if (e < NEDGES) {
        int r = rows[e];
        int p = atomicAdd(&cursor[r], 1);
        edges[p] = make_int2(cols[e], __float_as_int(vals[e]));
    }
}

// ---------------------------------------------------------------------------
// CSR SPMM (round-9 shape, known-good): 16 rows/block, 16 lanes per row,
// 4-deep unroll -> 4 independent gather chains. Fused relu + z-accumulate.
// ---------------------------------------------------------------------------
__global__ __launch_bounds__(256)
void spmm_csr_kernel(const int* __restrict__ row_ptr, const int2* __restrict__ edges,
                     const float* __restrict__ Xin,
                     float* __restrict__ A, float* __restrict__ z,
                     int dorelu, int writeA)
{
    int t = threadIdx.x;
    int r = blockIdx.x * 16 + (t >> 4);
    if (r >= N_NODES) return;
    int q = (t & 15) * 4;
    int e = row_ptr[r], end = row_ptr[r + 1];
    float4 acc = make_float4(0.f, 0.f, 0.f, 0.f);
    for (; e + 3 < end; e += 4) {
        int2 p0 = edges[e + 0], p1 = edges[e + 1];
        int2 p2 = edges[e + 2], p3 = edges[e + 3];
        float4 x0 = *reinterpret_cast<const float4*>(&Xin[(size_t)p0.x * HH + q]);
        float4 x1 = *reinterpret_cast<const float4*>(&Xin[(size_t)p1.x * HH + q]);
        float4 x2 = *reinterpret_cast<const float4*>(&Xin[(size_t)p2.x * HH + q]);
        float4 x3 = *reinterpret_cast<const float4*>(&Xin[(size_t)p3.x * HH + q]);
        float v0 = __int_as_float(p0.y), v1 = __int_as_float(p1.y);
        float v2 = __int_as_float(p2.y), v3 = __int_as_float(p3.y);
        acc.x += v0 * x0.x; acc.y += v0 * x0.y; acc.z += v0 * x0.z; acc.w += v0 * x0.w;
        acc.x += v1 * x1.x; acc.y += v1 * x1.y; acc.z += v1 * x1.z; acc.w += v1 * x1.w;
        acc.x += v2 * x2.x; acc.y += v2 * x2.y; acc.z += v2 * x2.z; acc.w += v2 * x2.w;
        acc.x += v3 * x3.x; acc.y += v3 * x3.y; acc.z += v3 * x3.z; acc.w += v3 * x3.w;
    }
    for (; e < end; ++e) {
        int2 p = edges[e];
        float v = __int_as_float(p.y);
        float4 x = *reinterpret_cast<const float4*>(&Xin[(size_t)p.x * HH + q]);
        acc.x += v * x.x; acc.y += v * x.y; acc.z += v * x.z; acc.w += v * x.w;
    }
    if (dorelu) {
        acc.x = fmaxf(acc.x, 0.f); acc.y = fmaxf(acc.y, 0.f);
        acc.z = fmaxf(acc.z, 0.f); acc.w = fmaxf(acc.w, 0.f);
    }
    size_t o = (size_t)r * HH + q;
    if (writeA) *reinterpret_cast<float4*>(&A[o]) = acc;
    float4 zz = *reinterpret_cast<float4*>(&z[o]);
    zz.x += acc.x; zz.y += acc.y; zz.z += acc.z; zz.w += acc.w;
    *reinterpret_cast<float4*>(&z[o]) = zz;
}

// ---------------------------------------------------------------------------
// Scorer: 32 queries per block, K=256 GEMM in 4 chunks of 64 with
// issue-early W preloading; float4 W staging.
// ---------------------------------------------------------------------------
#define SAs 268
#define SWs 68

__device__ __forceinline__ void loadWs(float4 wS[4], const float* __restrict__ W,
                                       int koff, int t)
{
#pragma unroll
    for (int i = 0; i < 4; ++i) {
        int idx = t + i * 256;
        int n = idx & 63, k4 = idx >> 6;
        wS[i] = *(const float4*)&W[(size_t)n * 256 + koff + k4 * 4];
    }
}

__device__ __forceinline__ void writeWs(float* __restrict__ Ws2, const float4 wS[4], int t)
{
#pragma unroll
    for (int i = 0; i < 4; ++i) {
        int idx = t + i * 256;
        int n = idx & 63, k4 = idx >> 6;
        Ws2[(k4 * 4 + 0) * SWs + n] = wS[i].x;
        Ws2[(k4 * 4 + 1) * SWs + n] = wS[i].y;
        Ws2[(k4 * 4 + 2) * SWs + n] = wS[i].z;
        Ws2[(k4 * 4 + 3) * SWs + n] = wS[i].w;
    }
}

__global__ __launch_bounds__(256)
void scorer_kernel(const float* __restrict__ z, const int* __restrict__ uidx,
                   const int* __restrict__ iidx,
                   const float* __restrict__ s1W, const float* __restrict__ s1b,
                   const float* __restrict__ s2W, const float* __restrict__ s2b,
                   const float* __restrict__ ubias, const float* __restrict__ ibias,
                   const float* __restrict__ gmean, float* __restrict__ out)
{
    __shared__ float As2[32 * SAs];  // 34.3 KB
    __shared__ float Ws2[64 * SWs];  // 17.4 KB

    const int t = threadIdx.x;
    const int row0 = blockIdx.x * 32;
    const int r0 = 2 * (t >> 4);
    const int n0 = 4 * (t & 15);

#pragma unroll
    for (int i = 0; i < 4; ++i) {
        int idx = t + i * 256;
        int half = idx >> 9;
        int rid = idx & 511;
        int r = rid >> 4, c4 = rid & 15;
        int q = row0 + r;
        int node = half ? (N_USERS + iidx[q]) : uidx[q];
        float4 v = *(const float4*)&z[(size_t)node * HH + c4 * 4];
        v.x *= (1.f / 3.f); v.y *= (1.f / 3.f); v.z *= (1.f / 3.f); v.w *= (1.f / 3.f);
        *(float4*)&As2[r * SAs + half * 64 + c4 * 4] = v;
    }
    float4 wS[4];
    loadWs(wS, s1W, 0, t);
    __syncthreads();
#pragma unroll
    for (int i = 0; i < 2; ++i) {
        int idx = t + i * 256;
        int r = idx >> 4, c4 = idx & 15;
        float4 a = *(const float4*)&As2[r * SAs + c4 * 4];
        float4 b = *(const float4*)&As2[r * SAs + 64 + c4 * 4];
        float4 p, d;
        p.x = a.x * b.x; p.y = a.y * b.y; p.z = a.z * b.z; p.w = a.w * b.w;
        d.x = fabsf(a.x - b.x); d.y = fabsf(a.y - b.y);
        d.z = fabsf(a.z - b.z); d.w = fabsf(a.w - b.w);
        *(float4*)&As2[r * SAs + 128 + c4 * 4] = p;
        *(float4*)&As2[r * SAs + 192 + c4 * 4] = d;
    }
    writeWs(Ws2, wS, t);
    __syncthreads();

    float acc[2][4] = {};
#pragma unroll
    for (int c = 0; c < 4; ++c) {
        if (c < 3) loadWs(wS, s1W, (c + 1) * 64, t);
#pragma unroll 2
        for (int k0 = 0; k0 < 64; k0 += 4) {
            float4 a0 = *(const float4*)&As2[(r0 + 0) * SAs + c * 64 + k0];
            float4 a1 = *(const float4*)&As2[(r0 + 1) * SAs + c * 64 + k0];
            float4 w[4];
            w[0] = *(const float4*)&Ws2[(k0 + 0) * SWs + n0];
            w[1] = *(const float4*)&Ws2[(k0 + 1) * SWs + n0];
            w[2] = *(const float4*)&Ws2[(k0 + 2) * SWs + n0];
            w[3] = *(const float4*)&Ws2[(k0 + 3) * SWs + n0];
            float av0[4] = { a0.x, a0.y, a0.z, a0.w };
            float av1[4] = { a1.x, a1.y, a1.z, a1.w };
#pragma unroll
            for (int kk = 0; kk < 4; ++kk) {
                acc[0][0] += av0[kk] * (&w[kk].x)[0];
                acc[0][1] += av0[kk] * (&w[kk].x)[1];
                acc[0][2] += av0[kk] * (&w[kk].x)[2];
                acc[0][3] += av0[kk] * (&w[kk].x)[3];
                acc[1][0] += av1[kk] * (&w[kk].x)[0];
                acc[1][1] += av1[kk] * (&w[kk].x)[1];
                acc[1][2] += av1[kk] * (&w[kk].x)[2];
                acc[1][3] += av1[kk] * (&w[kk].x)[3];
            }
        }
        __syncthreads();
        if (c < 3) {
            writeWs(Ws2, wS, t);
            __syncthreads();
        }
    }

    float b1v[4] = { s1b[n0], s1b[n0 + 1], s1b[n0 + 2], s1b[n0 + 3] };
    float s2w[4] = { s2W[n0], s2W[n0 + 1], s2W[n0 + 2], s2W[n0 + 3] };
    float pj[2];
#pragma unroll
    for (int j = 0; j < 2; ++j) {
        float p = 0.f;
#pragma unroll
        for (int i = 0; i < 4; ++i)
            p += fmaxf(acc[j][i] + b1v[i], 0.f) * s2w[i];
        p += __shfl_xor(p, 1); p += __shfl_xor(p, 2);
        p += __shfl_xor(p, 4); p += __shfl_xor(p, 8);
        pj[j] = p;
    }
    if ((t & 15) == 0) {
        float gm = gmean[0], b2 = s2b[0];
#pragma unroll
        for (int j = 0; j < 2; ++j) {
            int q = row0 + r0 + j;
            float pred = gm + ubias[uidx[q]] + ibias[iidx[q]] + b2 + pj[j];
            pred = fminf(fmaxf(pred, 1.f), 5.f);
            out[q] = pred;
        }
    }
}

// ---------------------------------------------------------------------------
extern "C" void kernel_launch(void* const* d_in, const int* in_sizes, int n_in,
                              void* d_out, int out_size, void* d_ws, size_t ws_size,
                              hipStream_t stream)
{
    const float* user_feat = (const float*)d_in[0];
    const float* item_feat = (const float*)d_in[1];
    const float* adj_vals  = (const float*)d_in[2];
    const float* ue_W  = (const float*)d_in[3];
    const float* ue_b  = (const float*)d_in[4];
    const float* ue_g  = (const float*)d_in[5];
    const float* ue_be = (const float*)d_in[6];
    const float* ie_W  = (const float*)d_in[7];
    const float* ie_b  = (const float*)d_in[8];
    const float* ie_g  = (const float*)d_in[9];
    const float* ie_be = (const float*)d_in[10];
    const float* uid_emb = (const float*)d_in[11];
    const float* iid_emb = (const float*)d_in[12];
    const float* uf_W  = (const float*)d_in[13];
    const float* uf_b  = (const float*)d_in[14];
    const float* uf_g  = (const float*)d_in[15];
    const float* uf_be = (const float*)d_in[16];
    const float* if_W  = (const float*)d_in[17];
    const float* if_b  = (const float*)d_in[18];
    const float* if_g  = (const float*)d_in[19];
    const float* if_be = (const float*)d_in[20];
    const float* gcn_W = (const float*)d_in[21];
    const float* gcn_b = (const float*)d_in[22];
    const float* ubias = (const float*)d_in[23];
    const float* ibias = (const float*)d_in[24];
    const float* s1_W  = (const float*)d_in[25];
    const float* s1_b  = (const float*)d_in[26];
    const float* s2_W  = (const float*)d_in[27];
    const float* s2_b  = (const float*)d_in[28];
    const float* gmean = (const float*)d_in[29];
    const int* adj_rows = (const int*)d_in[30];
    const int* adj_cols = (const int*)d_in[31];
    const int* user_idx = (const int*)d_in[32];
    const int* item_idx = (const int*)d_in[33];
    float* out = (float*)d_out;

    float* z = (float*)d_ws;                       // [N*64]
    float* A = z + (size_t)N_NODES * HH;           // [N*64]
    float* B = A + (size_t)N_NODES * HH;           // [N*64]
    int2* edges = (int2*)(B + (size_t)N_NODES * HH); // [E] packed (col,val)
    int* row_ptr = (int*)(edges + NEDGES);         // [N+1]
    int* cursor  = row_ptr + N_NODES + 4;          // [N] (histogram + cursors)
    int* bsum    = cursor + N_NODES;               // [SCAN_NBLK]

    const int ublocks = (N_USERS + 63) / 64;       // 1563
    const int iblocks = (N_ITEMS + 63) / 64;       // 782
    const int encB = ublocks + iblocks;            // 2345
    const int nblocks = (N_NODES + 63) / 64;       // 2344
    const int eblocks = (NEDGES + 255) / 256;      // 4688

    // ---- 1. zero histogram ----
    zero_int_kernel<<<512, 256, 0, stream>>>(cursor, N_NODES);

    // ---- 2. encoder (+gcn-L1 fused) interleaved with histogram ----
    // grid = 3*encB = 7035: bid%3==0 -> encode (2345), else hist (4690 >= 4688)
    encode_hist_kernel<<<3 * encB, 256, 0, stream>>>(
        ublocks,
        user_feat, item_feat, ue_W, ie_W, ue_b, ie_b, ue_g, ie_g, ue_be, ie_be,
        uid_emb, iid_emb, uf_W, if_W, uf_b, if_b, uf_g, if_g, uf_be, if_be,
        gcn_W, gcn_b, z, B, adj_rows, cursor);

    // ---- 3-5. CSR scan / finalize / scatter ----
    scan_blocks_kernel<<<SCAN_NBLK, 256, 0, stream>>>(cursor, row_ptr, bsum);
    finalize_kernel<<<SCAN_NBLK, 256, 0, stream>>>(row_ptr, bsum, cursor);
    scatter_kernel<<<eblocks, 256, 0, stream>>>(adj_rows, adj_cols, adj_vals,
                                                cursor, edges);

    // ---- 6. spmm layer 1: x1 = relu(spmm(B1)); A = x1; z += x1 ----
    const int sblocks = (N_NODES * 16 + 255) / 256;
    spmm_csr_kernel<<<sblocks, 256, 0, stream>>>(row_ptr, edges, B, A, z, 1, 1);

    // ---- 7. linear L2: B2 = A @ gW1.T + gb1 ----
    linear64_kernel<<<nblocks, 256, 0, stream>>>(
        A, gcn_W + HH * HH, gcn_b + HH, B, N_NODES);

    // ---- 8. spmm layer 2: z += spmm(B2) ----
    spmm_csr_kernel<<<sblocks, 256, 0, stream>>>(row_ptr, edges, B, A, z, 0, 0);

    // ---- 9. scorer ----
    scorer_kernel<<<NQ / 32, 256, 0, stream>>>(
        z, user_idx, item_idx, s1_W, s1_b, s2_W, s2_b, ubias, ibias, gmean, out);
}